// Round 4
// baseline (131.311 us; speedup 1.0000x reference)
//
#include <hip/hip_runtime.h>
#include <cstdint>

typedef unsigned long long u64;
typedef unsigned int u32;

#define NB 4096
#define NW 64            // 64-bit words per mask row
#define MM 20
#define HH 16
#define COND_THRES 0.2f
#define IOU_THRES 0.3f
#define PI_F  3.14159265358979323846f
#define PI4_F 0.78539816339744830962f

// ---- workspace layout (bytes) ----
#define WS_KEPT    0                           // u64[64] kept bitmask
#define WS_MASK    32768                       // u64[NB*NW] = 2 MiB
#define WS_BOX9S   (WS_MASK + NB*NW*8)         // float[NB*9]
#define WS_BEVS    (WS_BOX9S + NB*9*4)         // float4[NB]
#define WS_SCORES  (WS_BEVS + NB*16)           // float[NB]
#define WS_LABELS  (WS_SCORES + NB*4)          // int[NB]
#define WS_NBRW    (WS_LABELS + NB*4)          // u64[NB]

__device__ __forceinline__ u64 sort_key(float s, int i) {
  u32 sb = (s > COND_THRES) ? __float_as_uint(s) : 0u;
  return ((u64)(sb ^ 0xFFFFFFFFu) << 12) | (u64)i;
}

// ---------- K1: fused counting-rank + scatter + BEV, balanced: 256 blocks,
// 16 boxes per block, 16 chunk-counters per box (256 threads). Each block
// stages all 4096 keys in LDS (32 KB). Also zero-inits nbrw.
__global__ void __launch_bounds__(256) k_prep(const float* __restrict__ scores,
                                              const float* __restrict__ boxes9,
                                              const int* __restrict__ labels,
                                              float* __restrict__ box9s, float4* __restrict__ bevs,
                                              float* __restrict__ scoress, int* __restrict__ labelss,
                                              u64* __restrict__ nbrw) {
  #pragma clang fp contract(off)
  __shared__ u64 keys[NB];        // 32 KB
  __shared__ u32 part[16][16];
  int tid = threadIdx.x;
  for (int k = tid; k < NB; k += 256) keys[k] = sort_key(scores[k], k);
  __syncthreads();
  int bl = tid & 15;              // box-local 0..15
  int ch = tid >> 4;              // chunk 0..15 (256 keys each)
  u64 ki = keys[blockIdx.x * 16 + bl];
  int c = 0;
  #pragma unroll 16
  for (int t = 0; t < 256; ++t) c += (keys[(ch << 8) + t] < ki) ? 1 : 0;  // LDS broadcast
  part[bl][ch] = (u32)c;
  __syncthreads();
  if (tid < 16) {
    int i = blockIdx.x * 16 + tid;
    int r = 0;
    #pragma unroll
    for (int q = 0; q < 16; ++q) r += (int)part[tid][q];
    nbrw[i] = 0;
    float b[9];
    #pragma unroll
    for (int f = 0; f < 9; ++f) b[f] = boxes9[i * 9 + f];
    #pragma unroll
    for (int f = 0; f < 9; ++f) box9s[r * 9 + f] = b[f];
    float ang = b[6] - floorf(b[6] / PI_F + 0.5f) * PI_F;
    bool sw = fabsf(ang) >= PI4_F;
    float dx = sw ? b[4] : b[3];
    float dy = sw ? b[3] : b[4];
    bevs[r] = make_float4(b[0] - dx * 0.5f, b[1] - dy * 0.5f,
                          b[0] + dx * 0.5f, b[1] + dy * 0.5f);
    scoress[r] = scores[i];
    labelss[r] = labels[i];
  }
}

// ---------- K2: pairwise over-matrix (verbatim round-1, which passed).
__global__ void __launch_bounds__(64) k_mask(const float4* __restrict__ bevs,
                                             const int* __restrict__ labelss,
                                             const float* __restrict__ scoress,
                                             u64* __restrict__ mask,
                                             u64* __restrict__ nbrw) {
  #pragma clang fp contract(off)
  __shared__ float4 bj[64];
  __shared__ int lj[64];
  int t = threadIdx.x;
  int jt = blockIdx.x;
  int it = blockIdx.y;
  int j = jt * 64 + t;
  bj[t] = bevs[j];
  lj[t] = labelss[j];
  u64 vj = __ballot(scoress[j] > COND_THRES);   // valid mask of this j-tile
  int i = it * 64 + t;
  float4 a = bevs[i];
  int la = labelss[i];
  float area_a = (a.z - a.x) * (a.w - a.y);
  __syncthreads();
  u64 w = 0;
  #pragma unroll 8
  for (int kk = 0; kk < 64; ++kk) {
    float4 bb = bj[kk];
    float xmin = fmaxf(a.x, bb.x), ymin = fmaxf(a.y, bb.y);
    float xmax = fminf(a.z, bb.z), ymax = fminf(a.w, bb.w);
    float inter = fmaxf(xmax - xmin, 0.0f) * fmaxf(ymax - ymin, 0.0f);
    float area_b = (bb.z - bb.x) * (bb.w - bb.y);
    float iou = inter / fmaxf(area_a + area_b - inter, 1e-6f);
    if ((iou > IOU_THRES) && (la == lj[kk])) w |= (1ull << kk);
  }
  mask[(u64)i * NW + jt] = w;
  if (jt <= it) {
    u64 below = (jt < it) ? ~0ull : ((1ull << t) - 1ull);
    if (w & vj & below) atomicOr(&nbrw[i], 1ull << jt);
  }
}

// ---------- K3: EXACT one-pass Gauss-Seidel NMS.
// Suppression flows only low->high sorted index, so processing 64-box segments
// in ascending order with immediate publication needs NO convergence rounds:
// when segment s is processed, kept words 0..s-1 are FINAL. One wave holds the
// kept bitmask (lane w owns word w, accessed via shfl). Within-segment chains
// resolve by a small in-register ballot loop (>=1 decision/iter guaranteed:
// the lowest undecided box has all lower bits decided).
// Phase A (16 waves): build per-box compressed neighbor cache in LDS:
//   cs  = self-word overlap bits (below i), ce0/ce1 = first two ext words,
//   rem = ext words beyond two (rare), em = packed ext word indices.
__global__ void __launch_bounds__(1024) k_nms(const u64* __restrict__ mask,
                                              const u64* __restrict__ nbrw,
                                              const float* __restrict__ scoress,
                                              u64* __restrict__ keptOut) {
  __shared__ u64 csL[NB];        // 32 KB
  __shared__ u64 ce0L[NB];       // 32 KB
  __shared__ u64 ce1L[NB];       // 32 KB
  __shared__ u64 remL[NB];       // 32 KB
  __shared__ u32 emL[NB];        // 16 KB
  __shared__ u64 vwL[64];        // 512 B   (total ~144.5 KB < 160 KB)
  int tid = threadIdx.x;
  int lane = tid & 63;
  int waveId = tid >> 6;
  // ===== phase A: validity words + neighbor cache =====
  #pragma unroll
  for (int s4 = 0; s4 < 4; ++s4) {
    int i = tid + (s4 << 10);
    bool v = scoress[i] > COND_THRES;
    u64 vb = __ballot(v);
    if (lane == 0) vwL[waveId + (s4 << 4)] = vb;
  }
  #pragma unroll
  for (int s4 = 0; s4 < 4; ++s4) {
    int i = tid + (s4 << 10);
    int wi = i >> 6;
    u64 bit = 1ull << (i & 63);
    u64 t = nbrw[i];
    u64 cs = 0, c0 = 0, c1 = 0, rem = 0;
    u32 i0 = 0, i1 = 0; int n = 0;
    while (t) {
      int w = __builtin_ctzll(t);
      t &= t - 1;
      u64 m = mask[(u64)i * NW + w];
      if (w == wi) {
        cs = m & (bit - 1ull);               // below-bits of self word
      } else {                                // ext word (w < wi by construction)
        if (n == 0)      { c0 = m; i0 = (u32)w; }
        else if (n == 1) { c1 = m; i1 = (u32)w; }
        else rem |= 1ull << w;
        ++n;
      }
    }
    csL[i] = cs; ce0L[i] = c0; ce1L[i] = c1; remL[i] = rem;
    emL[i] = i0 | (i1 << 6);
  }
  __syncthreads();
  // ===== phase B: single-wave ordered scan =====
  if (tid < 64) {
    u64 keptW = 0;                 // lane w's FINAL kept word (set at segment w)
    u64 cs_c = csL[lane], ce0_c = ce0L[lane], ce1_c = ce1L[lane], rem_c = remL[lane];
    u32 em_c = emL[lane];
    u64 vws_c = vwL[0];
    for (int s = 0; s < 64; ++s) {
      // prefetch next segment (independent of kept state -> hoistable)
      u64 cs_n = 0, ce0_n = 0, ce1_n = 0, rem_n = 0, vws_n = 0; u32 em_n = 0;
      if (s < 63) {
        int ip = ((s + 1) << 6) | lane;
        cs_n = csL[ip]; ce0_n = ce0L[ip]; ce1_n = ce1L[ip];
        rem_n = remL[ip]; em_n = emL[ip]; vws_n = vwL[s + 1];
      }
      int w0 = (int)(em_c & 63u), w1 = (int)((em_c >> 6) & 63u);
      u64 k0 = __shfl(keptW, w0);             // kept word w0 (FINAL: w0 < s)
      u64 k1 = __shfl(keptW, w1);
      bool hk = ((ce0_c & k0) | (ce1_c & k1)) != 0ull;
      // rare overflow fallback (>=3 ext words)
      u64 rem = rem_c;
      while (__ballot(rem != 0ull) != 0ull) {
        int w = rem ? __builtin_ctzll(rem) : 0;
        u64 kws = __shfl(keptW, w);           // all lanes participate
        if (rem) {
          u64 m = mask[(u64)((s << 6) | lane) * NW + w];
          hk = hk || ((m & kws) != 0ull);
          rem &= rem - 1;
        }
      }
      // within-word Gauss-Seidel (register-only)
      u64 dw = ~vws_c;                        // invalids pre-decided, not kept
      u64 kw = 0;
      bool und = (vws_c >> lane) & 1ull;
      while (true) {
        bool dec = und && ((cs_c & ~dw) == 0ull);           // no undecided earlier
        bool keep = dec && !hk && ((cs_c & kw) == 0ull);    // no kept earlier
        dw |= __ballot(dec);
        kw |= __ballot(keep);
        und = und && !dec;
        if (__ballot(und) == 0ull) break;
      }
      if (lane == s) keptW = kw;              // publish word s (now final)
      cs_c = cs_n; ce0_c = ce0_n; ce1_c = ce1_n; rem_c = rem_n; em_c = em_n; vws_c = vws_n;
    }
    keptOut[lane] = keptW;
  }
}

// ---------- K4: per-box merge + all outputs (verbatim round-1, which passed).
__global__ void __launch_bounds__(64) k_merge(
    const u64* __restrict__ mask, const u64* __restrict__ keptG,
    const float* __restrict__ box9s, const float* __restrict__ scoress,
    const int* __restrict__ labelss,
    const float* __restrict__ w1, const float* __restrict__ b1,
    const float* __restrict__ w2, const float* __restrict__ b2,
    const float* __restrict__ w3, const float* __restrict__ b3,
    float* __restrict__ out) {
  #pragma clang fp contract(off)
  __shared__ int candList[MM];
  __shared__ float ob[MM][7];
  __shared__ float h1[7][HH];
  __shared__ float h2[7][HH];
  __shared__ float res[7];
  __shared__ u64 K[64];
  int i = blockIdx.x;
  int t = threadIdx.x;
  K[t] = keptG[t];
  __syncthreads();
  bool active = (K[i >> 6] >> (i & 63)) & 1ull;
  u64 wq = 0;
  int cnt = 0;
  if (active) {
    u64 w = mask[(u64)i * NW + t];
    int hiw = i >> 6;
    u64 below = (1ull << (i & 63)) - 1ull;   // bits k < i within word hiw
    while (w) {
      int b = __builtin_ctzll(w);
      w &= w - 1;
      int j = (t << 6) | b;
      if (scoress[j] > COND_THRES) {
        // claimed := exists kept k < i with over(k, j)
        const u64* rowj = mask + (u64)j * NW;
        u64 found = rowj[hiw] & K[hiw] & below;
        for (int ww = 0; ww < hiw; ++ww) found |= rowj[ww] & K[ww];
        if (!found) { wq |= (1ull << b); cnt++; }
      }
    }
  }
  int incl = cnt;
  #pragma unroll
  for (int off = 1; off < 64; off <<= 1) {
    int v = __shfl_up(incl, off);
    if (t >= off) incl += v;
  }
  int excl = incl - cnt;
  int count = __shfl(incl, 63);
  bool merged = active && (count > 1);
  if (merged && wq) {
    int pos = excl;
    u64 ww = wq;
    while (ww && pos < MM) {
      int b = __builtin_ctzll(ww);
      ww &= ww - 1;
      candList[pos++] = (t << 6) | b;
    }
  }
  __syncthreads();
  if (merged) {
    int nc = count < MM ? count : MM;
    if (t < MM) {
      if (t < nc) {
        int j = candList[t];
        #pragma unroll
        for (int f = 0; f < 7; ++f) ob[t][f] = box9s[j * 9 + f];
      } else {
        #pragma unroll
        for (int f = 0; f < 7; ++f) ob[t][f] = 0.0f;
      }
    }
    __syncthreads();
    for (int o = t; o < 7 * HH; o += 64) {
      int f = o >> 4, hh = o & 15;
      float acc = b1[hh];
      #pragma unroll
      for (int m = 0; m < MM; ++m) acc += ob[m][f] * w1[m * HH + hh];
      h1[f][hh] = fmaxf(acc, 0.0f);
    }
    __syncthreads();
    for (int o = t; o < 7 * HH; o += 64) {
      int f = o >> 4, oo = o & 15;
      float acc = b2[oo];
      #pragma unroll
      for (int k = 0; k < HH; ++k) acc += h1[f][k] * w2[k * HH + oo];
      h2[f][oo] = fmaxf(acc, 0.0f);
    }
    __syncthreads();
    if (t < 7) {
      float acc = b3[0];
      #pragma unroll
      for (int k = 0; k < HH; ++k) acc += h2[t][k] * w3[k];
      if (t >= 3 && t < 6) acc = fmaxf(acc, 1e-5f);
      res[t] = acc;
    }
    __syncthreads();
  }
  if (t < 9) {
    float v = box9s[i * 9 + t];
    if (merged && t < 7) v = res[t];
    out[i * 9 + t] = v;
  }
  if (t == 0) {
    out[NB * 9 + i]          = scoress[i];
    out[NB * 9 + NB + i]     = (float)labelss[i];
    out[NB * 9 + 2 * NB + i] = active ? 1.0f : 0.0f;
  }
}

extern "C" void kernel_launch(void* const* d_in, const int* in_sizes, int n_in,
                              void* d_out, int out_size, void* d_ws, size_t ws_size,
                              hipStream_t stream) {
  const float* boxes9 = (const float*)d_in[0];
  const float* scores = (const float*)d_in[1];
  const int*   labels = (const int*)d_in[2];
  const float* w1 = (const float*)d_in[3];
  const float* b1 = (const float*)d_in[4];
  const float* w2 = (const float*)d_in[5];
  const float* b2 = (const float*)d_in[6];
  const float* w3 = (const float*)d_in[7];
  const float* b3 = (const float*)d_in[8];
  char* ws = (char*)d_ws;
  u64*    kept    = (u64*)(ws + WS_KEPT);
  u64*    mask    = (u64*)(ws + WS_MASK);
  float*  box9s   = (float*)(ws + WS_BOX9S);
  float4* bevs    = (float4*)(ws + WS_BEVS);
  float*  scoress = (float*)(ws + WS_SCORES);
  int*    labelss = (int*)(ws + WS_LABELS);
  u64*    nbrw    = (u64*)(ws + WS_NBRW);
  float*  out     = (float*)d_out;

  hipLaunchKernelGGL(k_prep,  dim3(256),    dim3(256),  0, stream,
                     scores, boxes9, labels, box9s, bevs, scoress, labelss, nbrw);
  hipLaunchKernelGGL(k_mask,  dim3(64, 64), dim3(64),   0, stream,
                     bevs, labelss, scoress, mask, nbrw);
  hipLaunchKernelGGL(k_nms,   dim3(1),      dim3(1024), 0, stream,
                     mask, nbrw, scoress, kept);
  hipLaunchKernelGGL(k_merge, dim3(NB),     dim3(64),   0, stream,
                     mask, kept, box9s, scoress, labelss,
                     w1, b1, w2, b2, w3, b3, out);
}

// Round 5
// 119.554 us; speedup vs baseline: 1.0983x; 1.0983x over previous
//
#include <hip/hip_runtime.h>
#include <cstdint>

typedef unsigned long long u64;
typedef unsigned int u32;

#define NB 4096
#define NW 64            // 64-bit words per mask row
#define MM 20
#define HH 16
#define COND_THRES 0.2f
#define IOU_THRES 0.3f
#define PI_F  3.14159265358979323846f
#define PI4_F 0.78539816339744830962f

// ---- workspace layout (bytes) ----
#define WS_KEPT    0                           // u64[64] kept bitmask
#define WS_MASK    32768                       // u64[NB*NW] = 2 MiB
#define WS_BOX9S   (WS_MASK + NB*NW*8)         // float[NB*9]
#define WS_BEVS    (WS_BOX9S + NB*9*4)         // float4[NB]
#define WS_SCORES  (WS_BEVS + NB*16)           // float[NB]
#define WS_LABELS  (WS_SCORES + NB*4)          // int[NB]
#define WS_NBRW    (WS_LABELS + NB*4)          // u64[NB]

__device__ __forceinline__ u64 sort_key(float s, int i) {
  u32 sb = (s > COND_THRES) ? __float_as_uint(s) : 0u;
  return ((u64)(sb ^ 0xFFFFFFFFu) << 12) | (u64)i;
}

// ---------- K1: fused counting-rank + scatter + BEV. 256 blocks x 256 threads,
// 16 boxes per block, 16 chunk-counters per box (per-thread count work identical
// to the proven k_rank: 256 iterations). Each block stages all 4096 keys in LDS
// (32 KB). Also zero-inits nbrw.
__global__ void __launch_bounds__(256) k_prep(const float* __restrict__ scores,
                                              const float* __restrict__ boxes9,
                                              const int* __restrict__ labels,
                                              float* __restrict__ box9s, float4* __restrict__ bevs,
                                              float* __restrict__ scoress, int* __restrict__ labelss,
                                              u64* __restrict__ nbrw) {
  #pragma clang fp contract(off)
  __shared__ u64 keys[NB];        // 32 KB
  __shared__ u32 part[16][16];
  int tid = threadIdx.x;
  for (int k = tid; k < NB; k += 256) keys[k] = sort_key(scores[k], k);
  __syncthreads();
  int bl = tid & 15;              // box-local 0..15
  int ch = tid >> 4;              // chunk 0..15 (256 keys each)
  u64 ki = keys[blockIdx.x * 16 + bl];
  int c = 0;
  #pragma unroll 16
  for (int t = 0; t < 256; ++t) c += (keys[(ch << 8) + t] < ki) ? 1 : 0;  // LDS broadcast
  part[bl][ch] = (u32)c;
  __syncthreads();
  if (tid < 16) {
    int i = blockIdx.x * 16 + tid;
    int r = 0;
    #pragma unroll
    for (int q = 0; q < 16; ++q) r += (int)part[tid][q];
    nbrw[i] = 0;
    float b[9];
    #pragma unroll
    for (int f = 0; f < 9; ++f) b[f] = boxes9[i * 9 + f];
    #pragma unroll
    for (int f = 0; f < 9; ++f) box9s[r * 9 + f] = b[f];
    float ang = b[6] - floorf(b[6] / PI_F + 0.5f) * PI_F;
    bool sw = fabsf(ang) >= PI4_F;
    float dx = sw ? b[4] : b[3];
    float dy = sw ? b[3] : b[4];
    bevs[r] = make_float4(b[0] - dx * 0.5f, b[1] - dy * 0.5f,
                          b[0] + dx * 0.5f, b[1] + dy * 0.5f);
    scoress[r] = scores[i];
    labelss[r] = labels[i];
  }
}

// ---------- K2: pairwise over-matrix, SYMMETRIC-HALVED.
// IOU(i,j) is bit-exact symmetric (fmaxf/fminf commutative on finite inputs,
// fp add commutative, identical division & compare), so only tiles jt <= it are
// computed; tile (it,jt) with jt < it also emits the transposed tile (jt,it)
// via a 64-iter in-LDS bit-transpose. Upper-triangle blocks exit immediately.
// nbrw is updated only on the direct side (for row j, word it > jt is never
// "below"), exactly matching the full-matrix version's behavior.
__global__ void __launch_bounds__(64) k_mask(const float4* __restrict__ bevs,
                                             const int* __restrict__ labelss,
                                             const float* __restrict__ scoress,
                                             u64* __restrict__ mask,
                                             u64* __restrict__ nbrw) {
  #pragma clang fp contract(off)
  __shared__ float4 bj[64];
  __shared__ int lj[64];
  __shared__ u64 tw[64];
  int t = threadIdx.x;
  int jt = blockIdx.x;
  int it = blockIdx.y;
  if (jt > it) return;                          // symmetric half only
  int j = jt * 64 + t;
  bj[t] = bevs[j];
  lj[t] = labelss[j];
  u64 vj = __ballot(scoress[j] > COND_THRES);   // valid mask of this j-tile
  int i = it * 64 + t;
  float4 a = bevs[i];
  int la = labelss[i];
  float area_a = (a.z - a.x) * (a.w - a.y);
  __syncthreads();
  u64 w = 0;
  #pragma unroll 8
  for (int kk = 0; kk < 64; ++kk) {
    float4 bb = bj[kk];
    float xmin = fmaxf(a.x, bb.x), ymin = fmaxf(a.y, bb.y);
    float xmax = fminf(a.z, bb.z), ymax = fminf(a.w, bb.w);
    float inter = fmaxf(xmax - xmin, 0.0f) * fmaxf(ymax - ymin, 0.0f);
    float area_b = (bb.z - bb.x) * (bb.w - bb.y);
    float iou = inter / fmaxf(area_a + area_b - inter, 1e-6f);
    if ((iou > IOU_THRES) && (la == lj[kk])) w |= (1ull << kk);
  }
  mask[(u64)i * NW + jt] = w;
  {
    u64 below = (jt < it) ? ~0ull : ((1ull << t) - 1ull);
    if (w & vj & below) atomicOr(&nbrw[i], 1ull << jt);
  }
  if (jt < it) {
    // emit transposed tile: row j = jt*64+t, word it; bit k = bit t of lane k's w
    tw[t] = w;
    __syncthreads();
    u64 wT = 0;
    #pragma unroll 8
    for (int k = 0; k < 64; ++k) wT |= ((tw[k] >> t) & 1ull) << k;   // LDS broadcast
    mask[(u64)j * NW + it] = wT;
  }
}

// ---------- K3: greedy NMS fixpoint, atomic-free (verbatim round-1, proven).
__global__ void __launch_bounds__(1024) k_nms(const u64* __restrict__ mask,
                                              const u64* __restrict__ nbrw,
                                              const float* __restrict__ scoress,
                                              u64* __restrict__ keptOut) {
  __shared__ u64 decided[64], kept[64];
  __shared__ int wavePending[16];
  __shared__ int anyPending;
  int tid = threadIdx.x;
  int lane = tid & 63;
  int waveId = tid >> 6;
  u64 dcache[4], kcache[4];
  #pragma unroll
  for (int s = 0; s < 4; ++s) {
    int i = tid + (s << 10);
    bool v = scoress[i] > COND_THRES;
    u64 vw = __ballot(v);
    dcache[s] = ~vw;
    kcache[s] = 0;
    if (lane == 0) {
      int wi = waveId + (s << 4);
      decided[wi] = ~vw;
      kept[wi] = 0;
    }
  }
  u64 cw0[4], cw1[4];
  u32 meta[4];   // [5:0] idx0, [11:6] idx1, [13:12] n(min 2), [14] overflow
  #pragma unroll
  for (int s = 0; s < 4; ++s) {
    int i = tid + (s << 10);
    int wi = i >> 6;
    u64 bit = 1ull << (i & 63);
    u64 t = nbrw[i];
    int n = 0; u32 ovf = 0;
    u64 c0 = 0, c1 = 0; u32 i0 = 0, i1 = 0;
    while (t) {
      int w = __builtin_ctzll(t);
      t &= t - 1;
      u64 below = (w < wi) ? ~0ull : (bit - 1ull);
      u64 m = mask[(u64)i * NW + w] & below;
      if (n == 0)      { c0 = m; i0 = (u32)w; }
      else if (n == 1) { c1 = m; i1 = (u32)w; }
      else ovf = 1;
      ++n;
    }
    cw0[s] = c0; cw1[s] = c1;
    meta[s] = i0 | (i1 << 6) | ((u32)(n > 2 ? 2 : n) << 12) | (ovf << 14);
  }
  __syncthreads();
  while (true) {
    bool pend = false;
    #pragma unroll
    for (int s = 0; s < 4; ++s) {
      bool mine_und = !((dcache[s] >> lane) & 1ull);
      bool dec = false, keepme = false;
      if (mine_und) {
        bool hasU = false, hasK = false;
        u32 mt = meta[s];
        if (!(mt & (1u << 14))) {
          int n = (mt >> 12) & 3;
          if (n >= 1) {
            int w = mt & 63;
            u64 dw = decided[w], kw = kept[w];
            hasU = (cw0[s] & ~dw) != 0ull;
            hasK = (cw0[s] & kw) != 0ull;
          }
          if (n >= 2) {
            int w = (mt >> 6) & 63;
            u64 dw = decided[w], kw = kept[w];
            hasU = hasU || ((cw1[s] & ~dw) != 0ull);
            hasK = hasK || ((cw1[s] & kw) != 0ull);
          }
        } else {
          int i = tid + (s << 10);
          int wi = i >> 6;
          u64 bit = 1ull << (i & 63);
          u64 t = nbrw[i];
          while (t) {
            int w = __builtin_ctzll(t);
            t &= t - 1;
            u64 below = (w < wi) ? ~0ull : (bit - 1ull);
            u64 m = mask[(u64)i * NW + w] & below;
            hasU = hasU || ((m & ~decided[w]) != 0ull);
            hasK = hasK || ((m & kept[w]) != 0ull);
          }
        }
        dec = !hasU;
        keepme = !hasK;
      }
      u64 b_nd = __ballot(dec);
      u64 b_nk = __ballot(dec && keepme);
      dcache[s] |= b_nd;
      kcache[s] |= b_nk;
      pend |= (mine_und && !dec);
    }
    u64 pw = __ballot(pend);
    if (lane == 0) wavePending[waveId] = (pw != 0ull) ? 1 : 0;
    __syncthreads();
    if (lane == 0) {
      #pragma unroll
      for (int s = 0; s < 4; ++s) {
        int wi = waveId + (s << 4);
        decided[wi] = dcache[s];
        kept[wi] = kcache[s];
      }
    }
    if (tid == 0) {
      int any = 0;
      #pragma unroll
      for (int w = 0; w < 16; ++w) any |= wavePending[w];
      anyPending = any;
    }
    __syncthreads();
    if (!anyPending) break;
  }
  if (tid < 64) keptOut[tid] = kept[tid];
}

// ---------- K4: per-box merge + all outputs (verbatim round-1, proven).
__global__ void __launch_bounds__(64) k_merge(
    const u64* __restrict__ mask, const u64* __restrict__ keptG,
    const float* __restrict__ box9s, const float* __restrict__ scoress,
    const int* __restrict__ labelss,
    const float* __restrict__ w1, const float* __restrict__ b1,
    const float* __restrict__ w2, const float* __restrict__ b2,
    const float* __restrict__ w3, const float* __restrict__ b3,
    float* __restrict__ out) {
  #pragma clang fp contract(off)
  __shared__ int candList[MM];
  __shared__ float ob[MM][7];
  __shared__ float h1[7][HH];
  __shared__ float h2[7][HH];
  __shared__ float res[7];
  __shared__ u64 K[64];
  int i = blockIdx.x;
  int t = threadIdx.x;
  K[t] = keptG[t];
  __syncthreads();
  bool active = (K[i >> 6] >> (i & 63)) & 1ull;
  u64 wq = 0;
  int cnt = 0;
  if (active) {
    u64 w = mask[(u64)i * NW + t];
    int hiw = i >> 6;
    u64 below = (1ull << (i & 63)) - 1ull;   // bits k < i within word hiw
    while (w) {
      int b = __builtin_ctzll(w);
      w &= w - 1;
      int j = (t << 6) | b;
      if (scoress[j] > COND_THRES) {
        // claimed := exists kept k < i with over(k, j)
        const u64* rowj = mask + (u64)j * NW;
        u64 found = rowj[hiw] & K[hiw] & below;
        for (int ww = 0; ww < hiw; ++ww) found |= rowj[ww] & K[ww];
        if (!found) { wq |= (1ull << b); cnt++; }
      }
    }
  }
  int incl = cnt;
  #pragma unroll
  for (int off = 1; off < 64; off <<= 1) {
    int v = __shfl_up(incl, off);
    if (t >= off) incl += v;
  }
  int excl = incl - cnt;
  int count = __shfl(incl, 63);
  bool merged = active && (count > 1);
  if (merged && wq) {
    int pos = excl;
    u64 ww = wq;
    while (ww && pos < MM) {
      int b = __builtin_ctzll(ww);
      ww &= ww - 1;
      candList[pos++] = (t << 6) | b;
    }
  }
  __syncthreads();
  if (merged) {
    int nc = count < MM ? count : MM;
    if (t < MM) {
      if (t < nc) {
        int j = candList[t];
        #pragma unroll
        for (int f = 0; f < 7; ++f) ob[t][f] = box9s[j * 9 + f];
      } else {
        #pragma unroll
        for (int f = 0; f < 7; ++f) ob[t][f] = 0.0f;
      }
    }
    __syncthreads();
    for (int o = t; o < 7 * HH; o += 64) {
      int f = o >> 4, hh = o & 15;
      float acc = b1[hh];
      #pragma unroll
      for (int m = 0; m < MM; ++m) acc += ob[m][f] * w1[m * HH + hh];
      h1[f][hh] = fmaxf(acc, 0.0f);
    }
    __syncthreads();
    for (int o = t; o < 7 * HH; o += 64) {
      int f = o >> 4, oo = o & 15;
      float acc = b2[oo];
      #pragma unroll
      for (int k = 0; k < HH; ++k) acc += h1[f][k] * w2[k * HH + oo];
      h2[f][oo] = fmaxf(acc, 0.0f);
    }
    __syncthreads();
    if (t < 7) {
      float acc = b3[0];
      #pragma unroll
      for (int k = 0; k < HH; ++k) acc += h2[t][k] * w3[k];
      if (t >= 3 && t < 6) acc = fmaxf(acc, 1e-5f);
      res[t] = acc;
    }
    __syncthreads();
  }
  if (t < 9) {
    float v = box9s[i * 9 + t];
    if (merged && t < 7) v = res[t];
    out[i * 9 + t] = v;
  }
  if (t == 0) {
    out[NB * 9 + i]          = scoress[i];
    out[NB * 9 + NB + i]     = (float)labelss[i];
    out[NB * 9 + 2 * NB + i] = active ? 1.0f : 0.0f;
  }
}

extern "C" void kernel_launch(void* const* d_in, const int* in_sizes, int n_in,
                              void* d_out, int out_size, void* d_ws, size_t ws_size,
                              hipStream_t stream) {
  const float* boxes9 = (const float*)d_in[0];
  const float* scores = (const float*)d_in[1];
  const int*   labels = (const int*)d_in[2];
  const float* w1 = (const float*)d_in[3];
  const float* b1 = (const float*)d_in[4];
  const float* w2 = (const float*)d_in[5];
  const float* b2 = (const float*)d_in[6];
  const float* w3 = (const float*)d_in[7];
  const float* b3 = (const float*)d_in[8];
  char* ws = (char*)d_ws;
  u64*    kept    = (u64*)(ws + WS_KEPT);
  u64*    mask    = (u64*)(ws + WS_MASK);
  float*  box9s   = (float*)(ws + WS_BOX9S);
  float4* bevs    = (float4*)(ws + WS_BEVS);
  float*  scoress = (float*)(ws + WS_SCORES);
  int*    labelss = (int*)(ws + WS_LABELS);
  u64*    nbrw    = (u64*)(ws + WS_NBRW);
  float*  out     = (float*)d_out;

  hipLaunchKernelGGL(k_prep,  dim3(256),    dim3(256),  0, stream,
                     scores, boxes9, labels, box9s, bevs, scoress, labelss, nbrw);
  hipLaunchKernelGGL(k_mask,  dim3(64, 64), dim3(64),   0, stream,
                     bevs, labelss, scoress, mask, nbrw);
  hipLaunchKernelGGL(k_nms,   dim3(1),      dim3(1024), 0, stream,
                     mask, nbrw, scoress, kept);
  hipLaunchKernelGGL(k_merge, dim3(NB),     dim3(64),   0, stream,
                     mask, kept, box9s, scoress, labelss,
                     w1, b1, w2, b2, w3, b3, out);
}

// Round 6
// 112.841 us; speedup vs baseline: 1.1637x; 1.0595x over previous
//
#include <hip/hip_runtime.h>
#include <cstdint>

typedef unsigned long long u64;
typedef unsigned int u32;

#define NB 4096
#define NW 64            // 64-bit words per mask row
#define MM 20
#define HH 16
#define COND_THRES 0.2f
#define IOU_THRES 0.3f
#define PI_F  3.14159265358979323846f
#define PI4_F 0.78539816339744830962f

// ---- workspace layout (bytes) ----
#define WS_KEPT    0                           // u64[64] (unused now, kept for layout stability)
#define WS_MASK    32768                       // u64[NB*NW] = 2 MiB
#define WS_BOX9S   (WS_MASK + NB*NW*8)         // float[NB*9]
#define WS_BEVS    (WS_BOX9S + NB*9*4)         // float4[NB]
#define WS_SCORES  (WS_BEVS + NB*16)           // float[NB]
#define WS_LABELS  (WS_SCORES + NB*4)          // int[NB]
#define WS_NBRW    (WS_LABELS + NB*4)          // u64[NB]
#define WS_SUPSTEP (WS_NBRW + NB*8)            // int[NB]

__device__ __forceinline__ u64 sort_key(float s, int i) {
  u32 sb = (s > COND_THRES) ? __float_as_uint(s) : 0u;
  return ((u64)(sb ^ 0xFFFFFFFFu) << 12) | (u64)i;
}

// ---------- K1: fused counting-rank + scatter + BEV (verbatim round-5, passed).
__global__ void __launch_bounds__(256) k_prep(const float* __restrict__ scores,
                                              const float* __restrict__ boxes9,
                                              const int* __restrict__ labels,
                                              float* __restrict__ box9s, float4* __restrict__ bevs,
                                              float* __restrict__ scoress, int* __restrict__ labelss,
                                              u64* __restrict__ nbrw) {
  #pragma clang fp contract(off)
  __shared__ u64 keys[NB];        // 32 KB
  __shared__ u32 part[16][16];
  int tid = threadIdx.x;
  for (int k = tid; k < NB; k += 256) keys[k] = sort_key(scores[k], k);
  __syncthreads();
  int bl = tid & 15;              // box-local 0..15
  int ch = tid >> 4;              // chunk 0..15 (256 keys each)
  u64 ki = keys[blockIdx.x * 16 + bl];
  int c = 0;
  #pragma unroll 16
  for (int t = 0; t < 256; ++t) c += (keys[(ch << 8) + t] < ki) ? 1 : 0;  // LDS broadcast
  part[bl][ch] = (u32)c;
  __syncthreads();
  if (tid < 16) {
    int i = blockIdx.x * 16 + tid;
    int r = 0;
    #pragma unroll
    for (int q = 0; q < 16; ++q) r += (int)part[tid][q];
    nbrw[i] = 0;
    float b[9];
    #pragma unroll
    for (int f = 0; f < 9; ++f) b[f] = boxes9[i * 9 + f];
    #pragma unroll
    for (int f = 0; f < 9; ++f) box9s[r * 9 + f] = b[f];
    float ang = b[6] - floorf(b[6] / PI_F + 0.5f) * PI_F;
    bool sw = fabsf(ang) >= PI4_F;
    float dx = sw ? b[4] : b[3];
    float dy = sw ? b[3] : b[4];
    bevs[r] = make_float4(b[0] - dx * 0.5f, b[1] - dy * 0.5f,
                          b[0] + dx * 0.5f, b[1] + dy * 0.5f);
    scoress[r] = scores[i];
    labelss[r] = labels[i];
  }
}

// ---------- K2: pairwise over-matrix, SYMMETRIC-HALVED (round-5 body, passed),
// now launched on the 2080 lower-triangle tiles only (1D triangular decode).
__global__ void __launch_bounds__(64) k_mask(const float4* __restrict__ bevs,
                                             const int* __restrict__ labelss,
                                             const float* __restrict__ scoress,
                                             u64* __restrict__ mask,
                                             u64* __restrict__ nbrw) {
  #pragma clang fp contract(off)
  __shared__ float4 bj[64];
  __shared__ int lj[64];
  __shared__ u64 tw[64];
  int t = threadIdx.x;
  // triangular decode: largest it with it*(it+1)/2 <= b (float estimate + exact fix)
  int b = blockIdx.x;
  int it = (int)((sqrtf(8.0f * (float)b + 1.0f) - 1.0f) * 0.5f);
  while ((it + 1) * (it + 2) / 2 <= b) ++it;
  while (it * (it + 1) / 2 > b) --it;
  int jt = b - it * (it + 1) / 2;
  int j = jt * 64 + t;
  bj[t] = bevs[j];
  lj[t] = labelss[j];
  u64 vj = __ballot(scoress[j] > COND_THRES);   // valid mask of this j-tile
  int i = it * 64 + t;
  float4 a = bevs[i];
  int la = labelss[i];
  float area_a = (a.z - a.x) * (a.w - a.y);
  __syncthreads();
  u64 w = 0;
  #pragma unroll 8
  for (int kk = 0; kk < 64; ++kk) {
    float4 bb = bj[kk];
    float xmin = fmaxf(a.x, bb.x), ymin = fmaxf(a.y, bb.y);
    float xmax = fminf(a.z, bb.z), ymax = fminf(a.w, bb.w);
    float inter = fmaxf(xmax - xmin, 0.0f) * fmaxf(ymax - ymin, 0.0f);
    float area_b = (bb.z - bb.x) * (bb.w - bb.y);
    float iou = inter / fmaxf(area_a + area_b - inter, 1e-6f);
    if ((iou > IOU_THRES) && (la == lj[kk])) w |= (1ull << kk);
  }
  mask[(u64)i * NW + jt] = w;
  {
    u64 below = (jt < it) ? ~0ull : ((1ull << t) - 1ull);
    if (w & vj & below) atomicOr(&nbrw[i], 1ull << jt);
  }
  if (jt < it) {
    // emit transposed tile: row j = jt*64+t, word it; bit k = bit t of lane k's w
    tw[t] = w;
    __syncthreads();
    u64 wT = 0;
    #pragma unroll 8
    for (int k = 0; k < 64; ++k) wT |= ((tw[k] >> t) & 1ull) << k;   // LDS broadcast
    mask[(u64)j * NW + it] = wT;
  }
}

// ---------- K3: greedy NMS fixpoint (verbatim round-1, proven) + supstep tail.
// After the fixpoint, kept[] is final in LDS; each thread resolves supstep for
// its 4 boxes via the nbrw-restricted scan: min kept claimant k<j lives in a
// set word of nbrw[j] (kept subset of valid); if none, j itself (kept) or -1.
__global__ void __launch_bounds__(1024) k_nms(const u64* __restrict__ mask,
                                              const u64* __restrict__ nbrw,
                                              const float* __restrict__ scoress,
                                              int* __restrict__ supstep) {
  __shared__ u64 decided[64], kept[64];
  __shared__ int wavePending[16];
  __shared__ int anyPending;
  int tid = threadIdx.x;
  int lane = tid & 63;
  int waveId = tid >> 6;
  u64 dcache[4], kcache[4];
  bool validB[4];
  #pragma unroll
  for (int s = 0; s < 4; ++s) {
    int i = tid + (s << 10);
    bool v = scoress[i] > COND_THRES;
    validB[s] = v;
    u64 vw = __ballot(v);
    dcache[s] = ~vw;
    kcache[s] = 0;
    if (lane == 0) {
      int wi = waveId + (s << 4);
      decided[wi] = ~vw;
      kept[wi] = 0;
    }
  }
  u64 cw0[4], cw1[4];
  u32 meta[4];   // [5:0] idx0, [11:6] idx1, [13:12] n(min 2), [14] overflow
  #pragma unroll
  for (int s = 0; s < 4; ++s) {
    int i = tid + (s << 10);
    int wi = i >> 6;
    u64 bit = 1ull << (i & 63);
    u64 t = nbrw[i];
    int n = 0; u32 ovf = 0;
    u64 c0 = 0, c1 = 0; u32 i0 = 0, i1 = 0;
    while (t) {
      int w = __builtin_ctzll(t);
      t &= t - 1;
      u64 below = (w < wi) ? ~0ull : (bit - 1ull);
      u64 m = mask[(u64)i * NW + w] & below;
      if (n == 0)      { c0 = m; i0 = (u32)w; }
      else if (n == 1) { c1 = m; i1 = (u32)w; }
      else ovf = 1;
      ++n;
    }
    cw0[s] = c0; cw1[s] = c1;
    meta[s] = i0 | (i1 << 6) | ((u32)(n > 2 ? 2 : n) << 12) | (ovf << 14);
  }
  __syncthreads();
  while (true) {
    bool pend = false;
    #pragma unroll
    for (int s = 0; s < 4; ++s) {
      bool mine_und = !((dcache[s] >> lane) & 1ull);
      bool dec = false, keepme = false;
      if (mine_und) {
        bool hasU = false, hasK = false;
        u32 mt = meta[s];
        if (!(mt & (1u << 14))) {
          int n = (mt >> 12) & 3;
          if (n >= 1) {
            int w = mt & 63;
            u64 dw = decided[w], kw = kept[w];
            hasU = (cw0[s] & ~dw) != 0ull;
            hasK = (cw0[s] & kw) != 0ull;
          }
          if (n >= 2) {
            int w = (mt >> 6) & 63;
            u64 dw = decided[w], kw = kept[w];
            hasU = hasU || ((cw1[s] & ~dw) != 0ull);
            hasK = hasK || ((cw1[s] & kw) != 0ull);
          }
        } else {
          int i = tid + (s << 10);
          int wi = i >> 6;
          u64 bit = 1ull << (i & 63);
          u64 t = nbrw[i];
          while (t) {
            int w = __builtin_ctzll(t);
            t &= t - 1;
            u64 below = (w < wi) ? ~0ull : (bit - 1ull);
            u64 m = mask[(u64)i * NW + w] & below;
            hasU = hasU || ((m & ~decided[w]) != 0ull);
            hasK = hasK || ((m & kept[w]) != 0ull);
          }
        }
        dec = !hasU;
        keepme = !hasK;
      }
      u64 b_nd = __ballot(dec);
      u64 b_nk = __ballot(dec && keepme);
      dcache[s] |= b_nd;
      kcache[s] |= b_nk;
      pend |= (mine_und && !dec);
    }
    u64 pw = __ballot(pend);
    if (lane == 0) wavePending[waveId] = (pw != 0ull) ? 1 : 0;
    __syncthreads();
    if (lane == 0) {
      #pragma unroll
      for (int s = 0; s < 4; ++s) {
        int wi = waveId + (s << 4);
        decided[wi] = dcache[s];
        kept[wi] = kcache[s];
      }
    }
    if (tid == 0) {
      int any = 0;
      #pragma unroll
      for (int w = 0; w < 16; ++w) any |= wavePending[w];
      anyPending = any;
    }
    __syncthreads();
    if (!anyPending) break;
  }
  // ===== supstep tail: kept[] final in LDS (last publication pre-barrier) =====
  #pragma unroll
  for (int s = 0; s < 4; ++s) {
    int j = tid + (s << 10);
    int res;
    if (!validB[s]) {
      res = -1;
    } else {
      int wj = j >> 6;
      u64 bitbelow = (1ull << (j & 63)) - 1ull;
      res = j;                       // default: no earlier kept claimant -> j kept
      u64 t = nbrw[j];
      while (t) {
        int w = __builtin_ctzll(t);
        t &= t - 1;
        u64 m = mask[(u64)j * NW + w] & kept[w];
        if (w == wj) m &= bitbelow;  // only earlier-in-word claimants
        if (m) { res = (w << 6) + __builtin_ctzll(m); break; }  // words ascending -> min
      }
    }
    supstep[j] = res;
  }
}

// ---------- K4: per-box merge + all outputs (verbatim round-0 supstep version).
__global__ void __launch_bounds__(64) k_merge(
    const u64* __restrict__ mask, const int* __restrict__ supstep,
    const float* __restrict__ box9s, const float* __restrict__ scoress,
    const int* __restrict__ labelss,
    const float* __restrict__ w1, const float* __restrict__ b1,
    const float* __restrict__ w2, const float* __restrict__ b2,
    const float* __restrict__ w3, const float* __restrict__ b3,
    float* __restrict__ out) {
  #pragma clang fp contract(off)
  __shared__ int candList[MM];
  __shared__ float ob[MM][7];
  __shared__ float h1[7][HH];
  __shared__ float h2[7][HH];
  __shared__ float res[7];
  int i = blockIdx.x;
  int t = threadIdx.x;
  bool active = (supstep[i] == i);
  u64 wq = 0;
  int cnt = 0;
  if (active) {
    u64 w = mask[(u64)i * NW + t];
    while (w) {
      int b = __builtin_ctzll(w);
      w &= w - 1;
      int j = (t << 6) | b;
      if (supstep[j] >= i) { wq |= (1ull << b); cnt++; }
    }
  }
  int incl = cnt;
  #pragma unroll
  for (int off = 1; off < 64; off <<= 1) {
    int v = __shfl_up(incl, off);
    if (t >= off) incl += v;
  }
  int excl = incl - cnt;
  int count = __shfl(incl, 63);
  bool merged = active && (count > 1);
  if (merged && wq) {
    int pos = excl;
    u64 ww = wq;
    while (ww && pos < MM) {
      int b = __builtin_ctzll(ww);
      ww &= ww - 1;
      candList[pos++] = (t << 6) | b;
    }
  }
  __syncthreads();
  if (merged) {
    int nc = count < MM ? count : MM;
    if (t < MM) {
      if (t < nc) {
        int j = candList[t];
        #pragma unroll
        for (int f = 0; f < 7; ++f) ob[t][f] = box9s[j * 9 + f];
      } else {
        #pragma unroll
        for (int f = 0; f < 7; ++f) ob[t][f] = 0.0f;
      }
    }
    __syncthreads();
    for (int o = t; o < 7 * HH; o += 64) {
      int f = o >> 4, hh = o & 15;
      float acc = b1[hh];
      #pragma unroll
      for (int m = 0; m < MM; ++m) acc += ob[m][f] * w1[m * HH + hh];
      h1[f][hh] = fmaxf(acc, 0.0f);
    }
    __syncthreads();
    for (int o = t; o < 7 * HH; o += 64) {
      int f = o >> 4, oo = o & 15;
      float acc = b2[oo];
      #pragma unroll
      for (int k = 0; k < HH; ++k) acc += h1[f][k] * w2[k * HH + oo];
      h2[f][oo] = fmaxf(acc, 0.0f);
    }
    __syncthreads();
    if (t < 7) {
      float acc = b3[0];
      #pragma unroll
      for (int k = 0; k < HH; ++k) acc += h2[t][k] * w3[k];
      if (t >= 3 && t < 6) acc = fmaxf(acc, 1e-5f);
      res[t] = acc;
    }
    __syncthreads();
  }
  if (t < 9) {
    float v = box9s[i * 9 + t];
    if (merged && t < 7) v = res[t];
    out[i * 9 + t] = v;
  }
  if (t == 0) {
    out[NB * 9 + i]          = scoress[i];
    out[NB * 9 + NB + i]     = (float)labelss[i];
    out[NB * 9 + 2 * NB + i] = active ? 1.0f : 0.0f;
  }
}

extern "C" void kernel_launch(void* const* d_in, const int* in_sizes, int n_in,
                              void* d_out, int out_size, void* d_ws, size_t ws_size,
                              hipStream_t stream) {
  const float* boxes9 = (const float*)d_in[0];
  const float* scores = (const float*)d_in[1];
  const int*   labels = (const int*)d_in[2];
  const float* w1 = (const float*)d_in[3];
  const float* b1 = (const float*)d_in[4];
  const float* w2 = (const float*)d_in[5];
  const float* b2 = (const float*)d_in[6];
  const float* w3 = (const float*)d_in[7];
  const float* b3 = (const float*)d_in[8];
  char* ws = (char*)d_ws;
  u64*    mask    = (u64*)(ws + WS_MASK);
  float*  box9s   = (float*)(ws + WS_BOX9S);
  float4* bevs    = (float4*)(ws + WS_BEVS);
  float*  scoress = (float*)(ws + WS_SCORES);
  int*    labelss = (int*)(ws + WS_LABELS);
  u64*    nbrw    = (u64*)(ws + WS_NBRW);
  int*    supstep = (int*)(ws + WS_SUPSTEP);
  float*  out     = (float*)d_out;

  hipLaunchKernelGGL(k_prep,  dim3(256),  dim3(256),  0, stream,
                     scores, boxes9, labels, box9s, bevs, scoress, labelss, nbrw);
  hipLaunchKernelGGL(k_mask,  dim3(2080), dim3(64),   0, stream,
                     bevs, labelss, scoress, mask, nbrw);
  hipLaunchKernelGGL(k_nms,   dim3(1),    dim3(1024), 0, stream,
                     mask, nbrw, scoress, supstep);
  hipLaunchKernelGGL(k_merge, dim3(NB),   dim3(64),   0, stream,
                     mask, supstep, box9s, scoress, labelss,
                     w1, b1, w2, b2, w3, b3, out);
}

// Round 7
// 112.021 us; speedup vs baseline: 1.1722x; 1.0073x over previous
//
#include <hip/hip_runtime.h>
#include <cstdint>

typedef unsigned long long u64;
typedef unsigned int u32;

#define NB 4096
#define NW 64            // 64-bit words per mask row
#define MM 20
#define HH 16
#define COND_THRES 0.2f
#define IOU_THRES 0.3f
#define PI_F  3.14159265358979323846f
#define PI4_F 0.78539816339744830962f

// ---- workspace layout (bytes) ----
#define WS_KEPT    0                           // u64[64] (unused now, kept for layout stability)
#define WS_MASK    32768                       // u64[NB*NW] = 2 MiB
#define WS_BOX9S   (WS_MASK + NB*NW*8)         // float[NB*9]
#define WS_BEVS    (WS_BOX9S + NB*9*4)         // float4[NB]
#define WS_SCORES  (WS_BEVS + NB*16)           // float[NB]
#define WS_LABELS  (WS_SCORES + NB*4)          // int[NB]
#define WS_NBRW    (WS_LABELS + NB*4)          // u64[NB]
#define WS_SUPSTEP (WS_NBRW + NB*8)            // int[NB]

__device__ __forceinline__ u64 sort_key(float s, int i) {
  u32 sb = (s > COND_THRES) ? __float_as_uint(s) : 0u;
  return ((u64)(sb ^ 0xFFFFFFFFu) << 12) | (u64)i;
}

// ---------- K1: fused counting-rank + scatter + BEV (verbatim round-6, passed).
__global__ void __launch_bounds__(256) k_prep(const float* __restrict__ scores,
                                              const float* __restrict__ boxes9,
                                              const int* __restrict__ labels,
                                              float* __restrict__ box9s, float4* __restrict__ bevs,
                                              float* __restrict__ scoress, int* __restrict__ labelss,
                                              u64* __restrict__ nbrw) {
  #pragma clang fp contract(off)
  __shared__ u64 keys[NB];        // 32 KB
  __shared__ u32 part[16][16];
  int tid = threadIdx.x;
  for (int k = tid; k < NB; k += 256) keys[k] = sort_key(scores[k], k);
  __syncthreads();
  int bl = tid & 15;              // box-local 0..15
  int ch = tid >> 4;              // chunk 0..15 (256 keys each)
  u64 ki = keys[blockIdx.x * 16 + bl];
  int c = 0;
  #pragma unroll 16
  for (int t = 0; t < 256; ++t) c += (keys[(ch << 8) + t] < ki) ? 1 : 0;  // LDS broadcast
  part[bl][ch] = (u32)c;
  __syncthreads();
  if (tid < 16) {
    int i = blockIdx.x * 16 + tid;
    int r = 0;
    #pragma unroll
    for (int q = 0; q < 16; ++q) r += (int)part[tid][q];
    nbrw[i] = 0;
    float b[9];
    #pragma unroll
    for (int f = 0; f < 9; ++f) b[f] = boxes9[i * 9 + f];
    #pragma unroll
    for (int f = 0; f < 9; ++f) box9s[r * 9 + f] = b[f];
    float ang = b[6] - floorf(b[6] / PI_F + 0.5f) * PI_F;
    bool sw = fabsf(ang) >= PI4_F;
    float dx = sw ? b[4] : b[3];
    float dy = sw ? b[3] : b[4];
    bevs[r] = make_float4(b[0] - dx * 0.5f, b[1] - dy * 0.5f,
                          b[0] + dx * 0.5f, b[1] + dy * 0.5f);
    scoress[r] = scores[i];
    labelss[r] = labels[i];
  }
}

// ---------- K2: pairwise over-matrix, SYMMETRIC-HALVED, triangular grid
// (verbatim round-6, passed).
__global__ void __launch_bounds__(64) k_mask(const float4* __restrict__ bevs,
                                             const int* __restrict__ labelss,
                                             const float* __restrict__ scoress,
                                             u64* __restrict__ mask,
                                             u64* __restrict__ nbrw) {
  #pragma clang fp contract(off)
  __shared__ float4 bj[64];
  __shared__ int lj[64];
  __shared__ u64 tw[64];
  int t = threadIdx.x;
  // triangular decode: largest it with it*(it+1)/2 <= b (float estimate + exact fix)
  int b = blockIdx.x;
  int it = (int)((sqrtf(8.0f * (float)b + 1.0f) - 1.0f) * 0.5f);
  while ((it + 1) * (it + 2) / 2 <= b) ++it;
  while (it * (it + 1) / 2 > b) --it;
  int jt = b - it * (it + 1) / 2;
  int j = jt * 64 + t;
  bj[t] = bevs[j];
  lj[t] = labelss[j];
  u64 vj = __ballot(scoress[j] > COND_THRES);   // valid mask of this j-tile
  int i = it * 64 + t;
  float4 a = bevs[i];
  int la = labelss[i];
  float area_a = (a.z - a.x) * (a.w - a.y);
  __syncthreads();
  u64 w = 0;
  #pragma unroll 8
  for (int kk = 0; kk < 64; ++kk) {
    float4 bb = bj[kk];
    float xmin = fmaxf(a.x, bb.x), ymin = fmaxf(a.y, bb.y);
    float xmax = fminf(a.z, bb.z), ymax = fminf(a.w, bb.w);
    float inter = fmaxf(xmax - xmin, 0.0f) * fmaxf(ymax - ymin, 0.0f);
    float area_b = (bb.z - bb.x) * (bb.w - bb.y);
    float iou = inter / fmaxf(area_a + area_b - inter, 1e-6f);
    if ((iou > IOU_THRES) && (la == lj[kk])) w |= (1ull << kk);
  }
  mask[(u64)i * NW + jt] = w;
  {
    u64 below = (jt < it) ? ~0ull : ((1ull << t) - 1ull);
    if (w & vj & below) atomicOr(&nbrw[i], 1ull << jt);
  }
  if (jt < it) {
    // emit transposed tile: row j = jt*64+t, word it; bit k = bit t of lane k's w
    tw[t] = w;
    __syncthreads();
    u64 wT = 0;
    #pragma unroll 8
    for (int k = 0; k < 64; ++k) wT |= ((tw[k] >> t) & 1ull) << k;   // LDS broadcast
    mask[(u64)j * NW + it] = wT;
  }
}

// ---------- K3: greedy NMS, ORDERED SEGMENT PASSES (Gauss-Seidel).
// Suppression flows only low->high sorted index. Segment s (boxes
// [1024s,1024s+1024) = words [16s,16s+16)) maps exactly onto all 1024 threads.
// Converging segment 0 fully, then 1,2,3 makes every external dependency FINAL
// when read. Within a segment, each iteration provably decides >=1 box (the
// minimum undecided box has all earlier boxes decided), typical depth 3-6.
// One barrier per iteration: lane0 publishes its word + wavePending before the
// barrier; all threads read the 16 pending flags from LDS after it.
// Decision rule is verbatim from the proven fixpoint -> same unique solution.
// supstep is then computed from the REGISTER cache (no global re-reads except
// rare ovf boxes): min kept claimant = ctz(cw0&kept[w0]) else ctz(cw1&kept[w1])
// else j itself (cache words are below-masked, word indices ascending).
__global__ void __launch_bounds__(1024) k_nms(const u64* __restrict__ mask,
                                              const u64* __restrict__ nbrw,
                                              const float* __restrict__ scoress,
                                              int* __restrict__ supstep) {
  __shared__ u64 decided[64], kept[64];
  __shared__ int wavePending[16];
  int tid = threadIdx.x;
  int lane = tid & 63;
  int waveId = tid >> 6;
  bool validB[4];
  #pragma unroll
  for (int s = 0; s < 4; ++s) {
    int i = tid + (s << 10);
    bool v = scoress[i] > COND_THRES;
    validB[s] = v;
    u64 vw = __ballot(v);
    if (lane == 0) {
      decided[waveId + (s << 4)] = ~vw;   // invalids pre-decided, not kept
      kept[waveId + (s << 4)] = 0;
    }
  }
  // register cache: up to 2 masked neighbor words per owned box
  u64 cw0[4], cw1[4];
  u32 meta[4];   // [5:0] idx0, [11:6] idx1, [13:12] n(min 2), [14] overflow
  #pragma unroll
  for (int s = 0; s < 4; ++s) {
    int i = tid + (s << 10);
    int wi = i >> 6;
    u64 bit = 1ull << (i & 63);
    u64 t = nbrw[i];
    int n = 0; u32 ovf = 0;
    u64 c0 = 0, c1 = 0; u32 i0 = 0, i1 = 0;
    while (t) {
      int w = __builtin_ctzll(t);
      t &= t - 1;
      u64 below = (w < wi) ? ~0ull : (bit - 1ull);
      u64 m = mask[(u64)i * NW + w] & below;
      if (n == 0)      { c0 = m; i0 = (u32)w; }
      else if (n == 1) { c1 = m; i1 = (u32)w; }
      else ovf = 1;
      ++n;
    }
    cw0[s] = c0; cw1[s] = c1;
    meta[s] = i0 | (i1 << 6) | ((u32)(n > 2 ? 2 : n) << 12) | (ovf << 14);
  }
  __syncthreads();
  // ===== ordered segment passes =====
  for (int s = 0; s < 4; ++s) {
    const int i = tid + (s << 10);
    const int wi = waveId + (s << 4);
    const u64 bit = 1ull << (i & 63);
    const u32 mt = meta[s];
    bool und = validB[s];
    while (true) {
      bool dec = false, keepme = false;
      if (und) {
        bool hasU = false, hasK = false;
        if (!(mt & (1u << 14))) {
          int n = (mt >> 12) & 3;
          if (n >= 1) {
            int w = mt & 63;
            u64 dw = decided[w], kw = kept[w];
            hasU = (cw0[s] & ~dw) != 0ull;
            hasK = (cw0[s] & kw) != 0ull;
          }
          if (n >= 2) {
            int w = (mt >> 6) & 63;
            u64 dw = decided[w], kw = kept[w];
            hasU = hasU || ((cw1[s] & ~dw) != 0ull);
            hasK = hasK || ((cw1[s] & kw) != 0ull);
          }
        } else {
          u64 t = nbrw[i];
          while (t) {
            int w = __builtin_ctzll(t);
            t &= t - 1;
            u64 below = (w < wi) ? ~0ull : (bit - 1ull);
            u64 m = mask[(u64)i * NW + w] & below;
            hasU = hasU || ((m & ~decided[w]) != 0ull);
            hasK = hasK || ((m & kept[w]) != 0ull);
          }
        }
        dec = !hasU;
        keepme = !hasK;
      }
      u64 b_nd = __ballot(dec);
      u64 b_nk = __ballot(dec && keepme);
      bool pend = und && !dec;
      u64 pw = __ballot(pend);
      if (lane == 0) {
        decided[wi] |= b_nd;               // wave exclusively owns word wi
        kept[wi] |= b_nk;
        wavePending[waveId] = (pw != 0ull) ? 1 : 0;
      }
      und = pend;
      __syncthreads();
      int any = 0;
      #pragma unroll
      for (int w = 0; w < 16; ++w) any |= wavePending[w];   // LDS broadcast
      if (!any) break;
    }
  }
  // ===== supstep from cache (kept[] final in LDS) =====
  #pragma unroll
  for (int s = 0; s < 4; ++s) {
    int j = tid + (s << 10);
    int res;
    if (!validB[s]) {
      res = -1;
    } else {
      res = j;                       // no earlier kept claimant -> j itself kept
      u32 mt = meta[s];
      if (!(mt & (1u << 14))) {
        int n = (mt >> 12) & 3;
        if (n >= 1) {
          int w0 = mt & 63;
          u64 m0 = cw0[s] & kept[w0];
          if (m0) {
            res = (w0 << 6) + __builtin_ctzll(m0);          // min word, min bit
          } else if (n >= 2) {
            int w1 = (mt >> 6) & 63;
            u64 m1 = cw1[s] & kept[w1];
            if (m1) res = (w1 << 6) + __builtin_ctzll(m1);
          }
        }
      } else {
        // rare (>2 words): global re-scan, words ascending -> min claimant
        int wj = j >> 6;
        u64 bitbelow = (1ull << (j & 63)) - 1ull;
        u64 t = nbrw[j];
        while (t) {
          int w = __builtin_ctzll(t);
          t &= t - 1;
          u64 m = mask[(u64)j * NW + w] & kept[w];
          if (w == wj) m &= bitbelow;
          if (m) { res = (w << 6) + __builtin_ctzll(m); break; }
        }
      }
    }
    supstep[j] = res;
  }
}

// ---------- K4: per-box merge + all outputs (verbatim round-6, passed).
__global__ void __launch_bounds__(64) k_merge(
    const u64* __restrict__ mask, const int* __restrict__ supstep,
    const float* __restrict__ box9s, const float* __restrict__ scoress,
    const int* __restrict__ labelss,
    const float* __restrict__ w1, const float* __restrict__ b1,
    const float* __restrict__ w2, const float* __restrict__ b2,
    const float* __restrict__ w3, const float* __restrict__ b3,
    float* __restrict__ out) {
  #pragma clang fp contract(off)
  __shared__ int candList[MM];
  __shared__ float ob[MM][7];
  __shared__ float h1[7][HH];
  __shared__ float h2[7][HH];
  __shared__ float res[7];
  int i = blockIdx.x;
  int t = threadIdx.x;
  bool active = (supstep[i] == i);
  u64 wq = 0;
  int cnt = 0;
  if (active) {
    u64 w = mask[(u64)i * NW + t];
    while (w) {
      int b = __builtin_ctzll(w);
      w &= w - 1;
      int j = (t << 6) | b;
      if (supstep[j] >= i) { wq |= (1ull << b); cnt++; }
    }
  }
  int incl = cnt;
  #pragma unroll
  for (int off = 1; off < 64; off <<= 1) {
    int v = __shfl_up(incl, off);
    if (t >= off) incl += v;
  }
  int excl = incl - cnt;
  int count = __shfl(incl, 63);
  bool merged = active && (count > 1);
  if (merged && wq) {
    int pos = excl;
    u64 ww = wq;
    while (ww && pos < MM) {
      int b = __builtin_ctzll(ww);
      ww &= ww - 1;
      candList[pos++] = (t << 6) | b;
    }
  }
  __syncthreads();
  if (merged) {
    int nc = count < MM ? count : MM;
    if (t < MM) {
      if (t < nc) {
        int j = candList[t];
        #pragma unroll
        for (int f = 0; f < 7; ++f) ob[t][f] = box9s[j * 9 + f];
      } else {
        #pragma unroll
        for (int f = 0; f < 7; ++f) ob[t][f] = 0.0f;
      }
    }
    __syncthreads();
    for (int o = t; o < 7 * HH; o += 64) {
      int f = o >> 4, hh = o & 15;
      float acc = b1[hh];
      #pragma unroll
      for (int m = 0; m < MM; ++m) acc += ob[m][f] * w1[m * HH + hh];
      h1[f][hh] = fmaxf(acc, 0.0f);
    }
    __syncthreads();
    for (int o = t; o < 7 * HH; o += 64) {
      int f = o >> 4, oo = o & 15;
      float acc = b2[oo];
      #pragma unroll
      for (int k = 0; k < HH; ++k) acc += h1[f][k] * w2[k * HH + oo];
      h2[f][oo] = fmaxf(acc, 0.0f);
    }
    __syncthreads();
    if (t < 7) {
      float acc = b3[0];
      #pragma unroll
      for (int k = 0; k < HH; ++k) acc += h2[t][k] * w3[k];
      if (t >= 3 && t < 6) acc = fmaxf(acc, 1e-5f);
      res[t] = acc;
    }
    __syncthreads();
  }
  if (t < 9) {
    float v = box9s[i * 9 + t];
    if (merged && t < 7) v = res[t];
    out[i * 9 + t] = v;
  }
  if (t == 0) {
    out[NB * 9 + i]          = scoress[i];
    out[NB * 9 + NB + i]     = (float)labelss[i];
    out[NB * 9 + 2 * NB + i] = active ? 1.0f : 0.0f;
  }
}

extern "C" void kernel_launch(void* const* d_in, const int* in_sizes, int n_in,
                              void* d_out, int out_size, void* d_ws, size_t ws_size,
                              hipStream_t stream) {
  const float* boxes9 = (const float*)d_in[0];
  const float* scores = (const float*)d_in[1];
  const int*   labels = (const int*)d_in[2];
  const float* w1 = (const float*)d_in[3];
  const float* b1 = (const float*)d_in[4];
  const float* w2 = (const float*)d_in[5];
  const float* b2 = (const float*)d_in[6];
  const float* w3 = (const float*)d_in[7];
  const float* b3 = (const float*)d_in[8];
  char* ws = (char*)d_ws;
  u64*    mask    = (u64*)(ws + WS_MASK);
  float*  box9s   = (float*)(ws + WS_BOX9S);
  float4* bevs    = (float4*)(ws + WS_BEVS);
  float*  scoress = (float*)(ws + WS_SCORES);
  int*    labelss = (int*)(ws + WS_LABELS);
  u64*    nbrw    = (u64*)(ws + WS_NBRW);
  int*    supstep = (int*)(ws + WS_SUPSTEP);
  float*  out     = (float*)d_out;

  hipLaunchKernelGGL(k_prep,  dim3(256),  dim3(256),  0, stream,
                     scores, boxes9, labels, box9s, bevs, scoress, labelss, nbrw);
  hipLaunchKernelGGL(k_mask,  dim3(2080), dim3(64),   0, stream,
                     bevs, labelss, scoress, mask, nbrw);
  hipLaunchKernelGGL(k_nms,   dim3(1),    dim3(1024), 0, stream,
                     mask, nbrw, scoress, supstep);
  hipLaunchKernelGGL(k_merge, dim3(NB),   dim3(64),   0, stream,
                     mask, supstep, box9s, scoress, labelss,
                     w1, b1, w2, b2, w3, b3, out);
}